// Round 11
// baseline (96.395 us; speedup 1.0000x reference)
//
#include <hip/hip_runtime.h>
#include <stdint.h>

#define NN 8192
#define KD 512
#define BM 128
#define BK 32
#define NTILE (NN / BM)                 // 64
#define NTRI (NTILE * (NTILE + 1) / 2)  // 2080
#define NKT (KD / BK)                   // 16

typedef __bf16 bf16;
typedef __bf16 bf16x8 __attribute__((ext_vector_type(8)));
typedef float f32x4 __attribute__((ext_vector_type(4)));

// ---------------- kernel 1: row L2-normalize, fp32 -> bf16 ----------------
__global__ __launch_bounds__(256) void rownorm_kernel(const float* __restrict__ proto,
                                                      bf16* __restrict__ pn) {
    const int row  = blockIdx.x * 4 + (threadIdx.x >> 6);
    const int lane = threadIdx.x & 63;
    const float4* src = (const float4*)(proto + (size_t)row * KD) + lane * 2;
    const float4 v0 = src[0];
    const float4 v1 = src[1];
    float s = v0.x*v0.x + v0.y*v0.y + v0.z*v0.z + v0.w*v0.w
            + v1.x*v1.x + v1.y*v1.y + v1.z*v1.z + v1.w*v1.w;
#pragma unroll
    for (int off = 32; off; off >>= 1) s += __shfl_xor(s, off);
    const float inv = 1.0f / fmaxf(sqrtf(s), 1e-12f);
    bf16x8 o;
    o[0] = (bf16)(v0.x*inv); o[1] = (bf16)(v0.y*inv);
    o[2] = (bf16)(v0.z*inv); o[3] = (bf16)(v0.w*inv);
    o[4] = (bf16)(v1.x*inv); o[5] = (bf16)(v1.y*inv);
    o[6] = (bf16)(v1.z*inv); o[7] = (bf16)(v1.w*inv);
    *(bf16x8*)(pn + (size_t)row * KD + lane * 8) = o;
}

// -- kernel 2: C = leakyrelu(P P^T), symmetric; nt stores, vector epilogue --
__device__ __forceinline__ void gload_lds16(const bf16* g, bf16* l) {
    __builtin_amdgcn_global_load_lds(
        (const __attribute__((address_space(1))) void*)g,
        (__attribute__((address_space(3))) void*)l, 16, 0, 0);
}

__device__ __forceinline__ float lrelu(float v) {
    return (v >= 0.0f) ? v : 0.01f * v;
}

__global__ __launch_bounds__(256, 4) void gemm_sym_kernel(const bf16* __restrict__ P,
                                                          float* __restrict__ C) {
    // overlay: K-loop staging (32 KB) / sE [64][129] f32 (33.0 KB) /
    //          sM [128][65] f32 (33.3 KB)
    __shared__ __align__(16) unsigned char smem[33280];
    bf16*  sA = (bf16*)smem;               // [2][4096] elems
    bf16*  sB = (bf16*)(smem + 16384);     // [2][4096] elems
    float* sE = (float*)smem;              // [64][129]
    float* sM = (float*)smem;              // [128][65]

    // bijective XCD swizzle: 2080 = 8 x 260
    const int bid = blockIdx.x;
    const int swz = (bid & 7) * (NTRI / 8) + (bid >> 3);
    int tm = 0, rem = swz;
    while (rem >= NTILE - tm) { rem -= NTILE - tm; ++tm; }
    const int tn = tm + rem;

    const int tid  = threadIdx.x;
    const int w    = tid >> 6;
    const int lane = tid & 63;
    const int wr = w >> 1;               // wave row 0..1
    const int rowA0 = tm * BM;
    const int rowB0 = tn * BM;
    const int wm = wr * 64;
    const int wn = (w & 1) * 64;
    const int rr = lane & 15;
    const int h  = lane >> 4;

    const int chunk0 = w * 128 + lane;
    const bf16* g0 = P + (size_t)(chunk0 >> 2) * KD + (chunk0 & 3) * 8;
    const size_t offA = (size_t)rowA0 * KD;
    const size_t offB = (size_t)rowB0 * KD;
    const int ldsOff0 = w * 1024;
    const int ldsOff1 = w * 1024 + 512;

    f32x4 acc[4][4] = {};

#define STAGE(buf, kt)                                                        \
    do {                                                                      \
        gload_lds16(g0 + offA + (kt),           sA + (buf) * 4096 + ldsOff0); \
        gload_lds16(g0 + offA + 16 * KD + (kt), sA + (buf) * 4096 + ldsOff1); \
        gload_lds16(g0 + offB + (kt),           sB + (buf) * 4096 + ldsOff0); \
        gload_lds16(g0 + offB + 16 * KD + (kt), sB + (buf) * 4096 + ldsOff1); \
    } while (0)

#define COMPUTE(buf)                                                          \
    do {                                                                      \
        const bf16* ra_ = sA + (buf) * 4096;                                  \
        const bf16* rb_ = sB + (buf) * 4096;                                  \
        bf16x8 af[4], bfr[4];                                                 \
        _Pragma("unroll")                                                     \
        for (int m = 0; m < 4; ++m)                                           \
            af[m] = *(const bf16x8*)(ra_ + (wm + m * 16 + rr) * 32 + h * 8);  \
        _Pragma("unroll")                                                     \
        for (int n = 0; n < 4; ++n)                                           \
            bfr[n] = *(const bf16x8*)(rb_ + (wn + n * 16 + rr) * 32 + h * 8); \
        _Pragma("unroll")                                                     \
        for (int m = 0; m < 4; ++m)                                           \
            _Pragma("unroll")                                                 \
            for (int n = 0; n < 4; ++n)                                       \
                acc[m][n] = __builtin_amdgcn_mfma_f32_16x16x32_bf16(          \
                    af[m], bfr[n], acc[m][n], 0, 0, 0);                       \
    } while (0)

    STAGE(0, 0);
    __syncthreads();

#pragma unroll
    for (int t = 0; t < NKT; ++t) {
        if (t < NKT - 1) STAGE((t + 1) & 1, (t + 1) * BK);
        COMPUTE(t & 1);
        if (t < NKT - 1) __syncthreads();
    }

    // ---- epilogue: raw barriers (no vmcnt drains), nt full-line stores ----
    const int cr = h * 4;
    const int cc = rr;

#define LGKM0_BAR()                                                   \
    do {                                                              \
        asm volatile("s_waitcnt lgkmcnt(0)" ::: "memory");            \
        __builtin_amdgcn_s_barrier();                                 \
    } while (0)

#pragma unroll
    for (int H = 0; H < 2; ++H) {
        LGKM0_BAR();   // K-loop (H=0) / previous-half mirror (H=1) LDS reads done
        // normal dump (row-major) for the direct tile
        if (wr == H) {
#pragma unroll
            for (int m = 0; m < 4; ++m)
#pragma unroll
                for (int n = 0; n < 4; ++n)
#pragma unroll
                    for (int r = 0; r < 4; ++r)
                        sE[(m * 16 + cr + r) * 129 + wn + n * 16 + cc] =
                            lrelu(acc[m][n][r]);
        }
        LGKM0_BAR();

        // direct: 32 lanes = 512B contiguous per row (4 full 128B lines)
#pragma unroll
        for (int k = 0; k < 8; ++k) {
            const int seg = tid + k * 256;
            const int lr  = seg >> 5;
            const int c4  = (seg & 31) * 4;
            const f32x4 v = *(const f32x4*)&sE[lr * 129 + c4];
            __builtin_nontemporal_store(
                v, (f32x4*)&C[(size_t)(rowA0 + H * 64 + lr) * NN + rowB0 + c4]);
        }
        LGKM0_BAR();   // direct LDS reads done before transposed overwrite

        // transposed dump: acc quad r=0..3 -> contiguous i (float4 LDS write)
        if (wr == H) {
#pragma unroll
            for (int m = 0; m < 4; ++m)
#pragma unroll
                for (int n = 0; n < 4; ++n) {
                    f32x4 tv;
                    tv[0] = lrelu(acc[m][n][0]);
                    tv[1] = lrelu(acc[m][n][1]);
                    tv[2] = lrelu(acc[m][n][2]);
                    tv[3] = lrelu(acc[m][n][3]);
                    *(f32x4*)&sM[(wn + n * 16 + cc) * 65 + m * 16 + cr] = tv;
                }
        }
        LGKM0_BAR();

        // mirror (off-diag): per row j, 16 lanes = 256B contiguous (2 lines)
        if (tm != tn) {
#pragma unroll
            for (int rd = 0; rd < 8; ++rd) {
                const int j  = (tid >> 4) + rd * 16;
                const int i0 = (tid & 15) * 4;
                const f32x4 v = *(const f32x4*)&sM[j * 65 + i0];
                __builtin_nontemporal_store(
                    v, (f32x4*)&C[(size_t)(rowB0 + j) * NN + rowA0 + H * 64 + i0]);
            }
        }
    }
#undef STAGE
#undef COMPUTE
#undef LGKM0_BAR
}

extern "C" void kernel_launch(void* const* d_in, const int* in_sizes, int n_in,
                              void* d_out, int out_size, void* d_ws, size_t ws_size,
                              hipStream_t stream) {
    const float* proto = (const float*)d_in[1];
    float* C  = (float*)d_out;
    bf16* pn  = (bf16*)d_ws;   // 8 MB scratch

    rownorm_kernel<<<dim3(NN / 4), dim3(256), 0, stream>>>(proto, pn);
    gemm_sym_kernel<<<dim3(NTRI), dim3(256), 0, stream>>>(pn, C);
}